// Round 20
// baseline (417.979 us; speedup 1.0000x reference)
//
#include <hip/hip_runtime.h>
#include <math.h>

#define D_ 1024
#define H_ 16
#define HD_ 64
#define KW_ 4
#define I_ 2764
#define IP_ 2816              /* I padded to 22*128 */
#define NQKV_ 3328            /* q|k|v|gates fused N, padded to 13*256 */
#define NGU_ 5632             /* interleaved g/u N, 22*256 */
#define B_ 2
#define T_ 2048
#define BT_ (B_*T_)           /* 4096 */
#define ND_ (BT_*D_)          /* 4194304 */
#define NH_ (BT_*H_)          /* 65536 */
#define NCH_ 32               /* chunks per sequence (T/64) */
#define NG_ (32*NCH_)         /* 1024 (bh,chunk) groups */
#define EPS_ 1e-6f
#define GATE_BIAS_ 4.0f

typedef __attribute__((ext_vector_type(8))) short bf16x8;
typedef __attribute__((ext_vector_type(4))) float f32x4;

#define MFMA_(a,b,c) __builtin_amdgcn_mfma_f32_16x16x32_bf16(a, b, c, 0, 0, 0)
#define GLDS_(src, dst) __builtin_amdgcn_global_load_lds( \
    (const __attribute__((address_space(1))) void*)(src), \
    (__attribute__((address_space(3))) void*)(dst), 16, 0, 0)

/* ---------------- static buffers ---------------- */
__device__ float f_sc1[BT_];
__device__ float f_be[NH_];
__device__ float f_al[NH_];
__device__ float f_h[ND_];
__device__ float g_rs[NG_ * 256];
__device__ float g_BmT[(size_t)NG_*4096];            /* Bm^T [v][k'] f32 */
__device__ unsigned short g_Gqk[(size_t)NG_*4096];   /* [t][t'] */
__device__ unsigned short g_Y[(size_t)NG_*4096];     /* Y [t][k] */
__device__ unsigned short g_ZT[(size_t)NG_*4096];    /* Z^T [v][t] */
__device__ unsigned short g_A[(size_t)NG_*4096];     /* A [k'][k] */
__device__ unsigned short g_S[(size_t)NG_*4096];     /* entering S^T [v][k] */
__device__ unsigned short b_q[ND_];
__device__ unsigned short b_k[ND_];
__device__ unsigned short b_v[ND_];
__device__ unsigned short b_xc[ND_];
__device__ unsigned short b_o[ND_];
__device__ unsigned short b_hn[ND_];
__device__ unsigned short b_f[(size_t)BT_*IP_];
__device__ unsigned short b_wqkvT[(size_t)NQKV_*D_];
__device__ unsigned short b_woT[D_*D_];
__device__ unsigned short b_wguT[(size_t)NGU_*D_];
__device__ unsigned short b_wdT[(size_t)D_*IP_];

__device__ __forceinline__ unsigned short f2b(float x) {
  union { float f; unsigned u; } a; a.f = x;
  unsigned r = a.u + 0x7fff + ((a.u >> 16) & 1);
  return (unsigned short)(r >> 16);
}
__device__ __forceinline__ float b2f(unsigned short s) {
  union { unsigned u; float f; } a; a.u = ((unsigned)s) << 16; return a.f;
}

__device__ __forceinline__ const unsigned short* bsel(int id) {
  switch (id) {
    case 0: return b_xc;  case 1: return b_o;    case 2: return b_hn;
    case 3: return b_f;   case 4: return b_wqkvT; case 5: return b_woT;
    case 6: return b_wguT; default: return b_wdT;
  }
}
__device__ __forceinline__ unsigned short* bselw(int id) {
  return (unsigned short*)bsel(id);
}

/* ---------------- RMSNorm-1 scale only: f_sc1[row] ---------------- */
__global__ __launch_bounds__(256) void rmssc_k(const float* __restrict__ x) {
  int row = blockIdx.x;
  int tid = threadIdx.x;
  float4 v = ((const float4*)(x + (size_t)row * D_))[tid];
  float ss = v.x*v.x + v.y*v.y + v.z*v.z + v.w*v.w;
  #pragma unroll
  for (int o = 32; o > 0; o >>= 1) ss += __shfl_down(ss, o);
  __shared__ float sred[4];
  if ((tid & 63) == 0) sred[tid >> 6] = ss;
  __syncthreads();
  if (tid == 0)
    f_sc1[row] = rsqrtf((sred[0]+sred[1]+sred[2]+sred[3]) / (float)D_ + EPS_);
}

/* ---------------- RMSNorm 2 -> bf16 b_hn ---------------- */
__global__ __launch_bounds__(256) void rms2_k(const float* __restrict__ w) {
  int row = blockIdx.x;
  const float* xr = f_h + (size_t)row * D_;
  int tid = threadIdx.x;
  float4 v = ((const float4*)xr)[tid];
  float ss = v.x*v.x + v.y*v.y + v.z*v.z + v.w*v.w;
  #pragma unroll
  for (int o = 32; o > 0; o >>= 1) ss += __shfl_down(ss, o);
  __shared__ float sred[4];
  __shared__ float sscale;
  if ((tid & 63) == 0) sred[tid >> 6] = ss;
  __syncthreads();
  if (tid == 0)
    sscale = rsqrtf((sred[0]+sred[1]+sred[2]+sred[3]) / (float)D_ + EPS_);
  __syncthreads();
  float s = sscale;
  float4 wv = ((const float4*)w)[tid];
  unsigned short* orow = b_hn + (size_t)row * D_ + tid * 4;
  orow[0] = f2b(v.x*s*wv.x); orow[1] = f2b(v.y*s*wv.y);
  orow[2] = f2b(v.z*s*wv.z); orow[3] = f2b(v.w*s*wv.w);
}

/* ---------------- causal depthwise conv + inline rmsnorm + SiLU -> b_xc ---------------- */
__global__ __launch_bounds__(256) void conv2_k(const float* __restrict__ x,
                                               const float* __restrict__ cw,
                                               const float* __restrict__ cb,
                                               const float* __restrict__ n1w) {
  int idx = blockIdx.x * 256 + threadIdx.x;
  int d = idx & (D_ - 1);
  int bt = idx >> 10;
  int t = bt & (T_ - 1);
  float wd = n1w[d];
  float acc = cb[d];
  #pragma unroll
  for (int j = 0; j < KW_; j++) {
    int tt = t - (KW_ - 1) + j;
    if (tt >= 0) {
      int off = j - (KW_ - 1);
      acc += x[(size_t)idx + (size_t)off * D_] * f_sc1[bt + off] * wd * cw[d * KW_ + j];
    }
  }
  float s = acc / (1.f + expf(-acc));
  b_xc[idx] = f2b(s);
}

/* ---------------- fused QKV+gates weight cast+transpose ---------------- */
__global__ __launch_bounds__(256) void castTqkv_k(const float* __restrict__ wq,
                                                  const float* __restrict__ wk,
                                                  const float* __restrict__ wv,
                                                  const float* __restrict__ wb,
                                                  const float* __restrict__ wa) {
  __shared__ float s[64][65];
  int n0 = blockIdx.x * 64, k0 = blockIdx.y * 64;
  int tx = threadIdx.x & 63, ty = threadIdx.x >> 6;
  int nn = n0 + tx;
  const float* src = nullptr; int col = 0, ld = 1024;
  if (nn < 1024)      { src = wq; col = nn; }
  else if (nn < 2048) { src = wk; col = nn - 1024; }
  else if (nn < 3072) { src = wv; col = nn - 2048; }
  else if (nn < 3088) { src = wb; col = nn - 3072; ld = 16; }
  else if (nn < 3104) { src = wa; col = nn - 3088; ld = 16; }
  #pragma unroll
  for (int j = ty; j < 64; j += 4)
    s[j][tx] = src ? src[(size_t)(k0 + j) * ld + col] : 0.f;
  __syncthreads();
  #pragma unroll
  for (int j = ty; j < 64; j += 4)
    b_wqkvT[(size_t)(n0 + j) * D_ + k0 + tx] = f2b(s[tx][j]);
}

/* ---------------- interleaved G/U weight cast ---------------- */
__global__ __launch_bounds__(256) void castTgu_k(const float* __restrict__ wg,
                                                 const float* __restrict__ wu) {
  __shared__ float s[64][65];
  int n0 = blockIdx.x * 64, k0 = blockIdx.y * 64;
  int tx = threadIdx.x & 63, ty = threadIdx.x >> 6;
  int nn = n0 + tx;
  int inner = nn & 31;
  int col = (nn >> 5) * 16 + (inner & 15);
  const float* src = (inner < 16) ? wg : wu;
  bool ok = (col < I_);
  #pragma unroll
  for (int j = ty; j < 64; j += 4)
    s[j][tx] = ok ? src[(size_t)(k0 + j) * I_ + col] : 0.f;
  __syncthreads();
  #pragma unroll
  for (int j = ty; j < 64; j += 4)
    b_wguT[(size_t)(n0 + j) * D_ + k0 + tx] = f2b(s[tx][j]);
}

/* ---------------- plain weight cast+transpose ---------------- */
__global__ __launch_bounds__(256) void castT_k(const float* __restrict__ W,
                                               int K, int N, int outid, int Kp) {
  __shared__ float s[64][65];
  unsigned short* out = bselw(outid);
  int k0 = blockIdx.y * 64, n0 = blockIdx.x * 64;
  int tx = threadIdx.x & 63, ty = threadIdx.x >> 6;
  #pragma unroll
  for (int j = ty; j < 64; j += 4) {
    int kk = k0 + j, nn = n0 + tx;
    s[j][tx] = (kk < K && nn < N) ? W[(size_t)kk * N + nn] : 0.f;
  }
  __syncthreads();
  #pragma unroll
  for (int j = ty; j < 64; j += 4)
    out[(size_t)(n0 + j) * Kp + k0 + tx] = f2b(s[tx][j]);
}

/* ---------------- 256x256 8-wave GEMM, BK=64, 4-phase interleave v2 ----------------
 * Early staging (p0: all A of t+1, p1: all B), per-phase barrier+lgkmcnt+
 * setprio'd 16-MFMA cluster, boundary vmcnt(0) covered by 2-3 phases.
 * mode 0: QKV epilogue; mode 1: GU swiglu epilogue.                         */
__global__ __launch_bounds__(512) void gemm256(int aid, int bid, int Kp, int mode) {
  __shared__ __align__(16) unsigned short Al[2][256 * 64];
  __shared__ __align__(16) unsigned short Bl[2][256 * 64];
  const unsigned short* A = bsel(aid);
  const unsigned short* Bt = bsel(bid);
  int tid = threadIdx.x;
  int nbx = gridDim.x;
  int nwg = nbx * gridDim.y;
  int lid = blockIdx.y * nbx + blockIdx.x;
  int cpx = nwg >> 3;
  int swzb = (lid & 7) * cpx + (lid >> 3);
  int m0 = (swzb / nbx) * 256, n0 = (swzb % nbx) * 256;
  int w = tid >> 6, lane = tid & 63;
  int wm = (w >> 2) * 128, wn = (w & 3) * 64;
  const int l15 = lane & 15, lg = lane >> 4;
  int srow = tid >> 3;                       /* staging row-in-64 (0..63) */
  int scol = ((tid & 7) ^ (srow & 7)) * 8;   /* pre-swizzled source slot  */
  int ldsw = w * 512;                        /* wave-uniform dst offset   */
  const unsigned short* Arow = A + (size_t)m0 * Kp;
  const unsigned short* Brow = Bt + (size_t)n0 * Kp;
  int swz0 = ((0 + lg) ^ (l15 & 7)) * 8;     /* read slot, k-half 0 */
  int swz1 = ((4 + lg) ^ (l15 & 7)) * 8;     /* read slot, k-half 1 */
  f32x4 acc[8][4] = {};
  const int nt = Kp >> 6;
  /* prologue: stage tile 0 fully */
  #pragma unroll
  for (int i = 0; i < 4; i++) {
    GLDS_(Arow + (size_t)(i * 64 + srow) * Kp + scol, Al[0] + i * 4096 + ldsw);
    GLDS_(Brow + (size_t)(i * 64 + srow) * Kp + scol, Bl[0] + i * 4096 + ldsw);
  }
  asm volatile("s_waitcnt vmcnt(0)" ::: "memory");
  __builtin_amdgcn_s_barrier();
  for (int t = 0; t < nt; t++) {
    int cur = t & 1;
    int k0n = (t + 1) << 6;
    bool more = (t + 1 < nt);
    bf16x8 bf0[4], bf1[4];
    /* ---- phase 0: ds bf(8)+af pair0(4); stage A-half0+A-half1 of t+1 ---- */
    {
      #pragma unroll
      for (int j = 0; j < 4; j++) {
        bf0[j] = *(const bf16x8*)&Bl[cur][(wn + j * 16 + l15) * 64 + swz0];
        bf1[j] = *(const bf16x8*)&Bl[cur][(wn + j * 16 + l15) * 64 + swz1];
      }
      bf16x8 a0k0 = *(const bf16x8*)&Al[cur][(wm + 0 * 16 + l15) * 64 + swz0];
      bf16x8 a0k1 = *(const bf16x8*)&Al[cur][(wm + 0 * 16 + l15) * 64 + swz1];
      bf16x8 a1k0 = *(const bf16x8*)&Al[cur][(wm + 1 * 16 + l15) * 64 + swz0];
      bf16x8 a1k1 = *(const bf16x8*)&Al[cur][(wm + 1 * 16 + l15) * 64 + swz1];
      if (more) {
        GLDS_(Arow + (size_t)(0 * 64 + srow) * Kp + k0n + scol, Al[cur ^ 1] + 0 * 4096 + ldsw);
        GLDS_(Arow + (size_t)(1 * 64 + srow) * Kp + k0n + scol, Al[cur ^ 1] + 1 * 4096 + ldsw);
        GLDS_(Arow + (size_t)(2 * 64 + srow) * Kp + k0n + scol, Al[cur ^ 1] + 2 * 4096 + ldsw);
        GLDS_(Arow + (size_t)(3 * 64 + srow) * Kp + k0n + scol, Al[cur ^ 1] + 3 * 4096 + ldsw);
      }
      __builtin_amdgcn_sched_barrier(0);
      __builtin_amdgcn_s_barrier();
      asm volatile("s_waitcnt lgkmcnt(0)" ::: "memory");
      __builtin_amdgcn_sched_barrier(0);
      __builtin_amdgcn_s_setprio(1);
      #pragma unroll
      for (int j = 0; j < 4; j++) {
        acc[0][j] = MFMA_(a0k0, bf0[j], acc[0][j]);
        acc[0][j] = MFMA_(a0k1, bf1[j], acc[0][j]);
        acc[1][j] = MFMA_(a1k0, bf0[j], acc[1][j]);
        acc[1][j] = MFMA_(a1k1, bf1[j], acc[1][j]);
      }
      __builtin_amdgcn_s_setprio(0);
      __builtin_amdgcn_sched_barrier(0);
      __builtin_amdgcn_s_barrier();
      __builtin_amdgcn_sched_barrier(0);
    }
    /* ---- phases 1..3: ds af pair p; p1 stages B-half0+B-half1 ---- */
    #pragma unroll
    for (int p = 1; p < 4; p++) {
      bf16x8 a0k0 = *(const bf16x8*)&Al[cur][(wm + (2 * p) * 16 + l15) * 64 + swz0];
      bf16x8 a0k1 = *(const bf16x8*)&Al[cur][(wm + (2 * p) * 16 + l15) * 64 + swz1];
      bf16x8 a1k0 = *(const bf16x8*)&Al[cur][(wm + (2 * p + 1) * 16 + l15) * 64 + swz0];
      bf16x8 a1k1 = *(const bf16x8*)&Al[cur][(wm + (2 * p + 1) * 16 + l15) * 64 + swz1];
      if (more && p == 1) {
        GLDS_(Brow + (size_t)(0 * 64 + srow) * Kp + k0n + scol, Bl[cur ^ 1] + 0 * 4096 + ldsw);
        GLDS_(Brow + (size_t)(1 * 64 + srow) * Kp + k0n + scol, Bl[cur ^ 1] + 1 * 4096 + ldsw);
        GLDS_(Brow + (size_t)(2 * 64 + srow) * Kp + k0n + scol, Bl[cur ^ 1] + 2 * 4096 + ldsw);
        GLDS_(Brow + (size_t)(3 * 64 + srow) * Kp + k0n + scol, Bl[cur ^ 1] + 3 * 4096 + ldsw);
      }
      __builtin_amdgcn_sched_barrier(0);
      __builtin_amdgcn_s_barrier();
      asm volatile("s_waitcnt lgkmcnt(0)" ::: "memory");
      __builtin_amdgcn_sched_barrier(0);
      __builtin_amdgcn_s_setprio(1);
      #pragma unroll
      for (int j = 0; j < 4; j++) {
        acc[2 * p][j]     = MFMA_(a0k0, bf0[j], acc[2 * p][j]);
        acc[2 * p][j]     = MFMA_(a0k1, bf1[j], acc[2 * p][j]);
        acc[2 * p + 1][j] = MFMA_(a1k0, bf0[j], acc[2 * p + 1][j]);
        acc[2 * p + 1][j] = MFMA_(a1k1, bf1[j], acc[2 * p + 1][j]);
      }
      __builtin_amdgcn_s_setprio(0);
      __builtin_amdgcn_sched_barrier(0);
      if (p == 3 && more)
        asm volatile("s_waitcnt vmcnt(0)" ::: "memory");
      __builtin_amdgcn_s_barrier();
      __builtin_amdgcn_sched_barrier(0);
    }
  }
  int C0 = n0 + wn;
  if (mode == 0) {
    if (C0 < 2048) {                     /* q or k: per-head l2norm -> bf16 */
      unsigned short* dst = (C0 < 1024) ? b_q : b_k;
      int cbase = C0 & 1023;
      #pragma unroll
      for (int i = 0; i < 8; i++) {
        int r0i = m0 + wm + i * 16 + lg * 4;
        #pragma unroll
        for (int r = 0; r < 4; r++) {
          float ss = acc[i][0][r]*acc[i][0][r] + acc[i][1][r]*acc[i][1][r]
                   + acc[i][2][r]*acc[i][2][r] + acc[i][3][r]*acc[i][3][r];
          ss += __shfl_xor(ss, 1); ss += __shfl_xor(ss, 2);
          ss += __shfl_xor(ss, 4); ss += __shfl_xor(ss, 8);
          float sc = rsqrtf(ss + EPS_);
          #pragma unroll
          for (int j = 0; j < 4; j++)
            dst[(size_t)(r0i + r) * D_ + cbase + j * 16 + l15] = f2b(acc[i][j][r] * sc);
        }
      }
    } else if (C0 < 3072) {              /* v -> bf16 */
      int cbase = C0 & 1023;
      #pragma unroll
      for (int i = 0; i < 8; i++) {
        int r0i = m0 + wm + i * 16 + lg * 4;
        #pragma unroll
        for (int j = 0; j < 4; j++)
          #pragma unroll
          for (int r = 0; r < 4; r++)
            b_v[(size_t)(r0i + r) * D_ + cbase + j * 16 + l15] = f2b(acc[i][j][r]);
      }
    } else if (C0 == 3072) {             /* beta (j=0) / alpha (j=1); j=2,3 pad */
      #pragma unroll
      for (int i = 0; i < 8; i++) {
        int r0i = m0 + wm + i * 16 + lg * 4;
        #pragma unroll
        for (int r = 0; r < 4; r++) {
          float vb = acc[i][0][r];
          f_be[(size_t)(r0i + r) * H_ + l15] = 1.f / (1.f + expf(-vb));
          float va = acc[i][1][r] + GATE_BIAS_;
          f_al[(size_t)(r0i + r) * H_ + l15] = 1.f / (1.f + expf(-va));
        }
      }
    }                                    /* C0 > 3072: pad, skip */
  } else {                               /* mode 1: swiglu -> b_f */
    #pragma unroll
    for (int i = 0; i < 8; i++) {
      int r0i = m0 + wm + i * 16 + lg * 4;
      #pragma unroll
      for (int jp = 0; jp < 2; jp++) {
        int j = jp * 2;
        int Lbase = ((C0 + j * 16) >> 5) * 16;
        #pragma unroll
        for (int r = 0; r < 4; r++) {
          float g = acc[i][j][r], u = acc[i][j + 1][r];
          float sg = g / (1.f + expf(-g));
          b_f[(size_t)(r0i + r) * IP_ + Lbase + l15] = f2b(sg * u);
        }
      }
    }
  }
}

/* ---------------- bf16 MFMA GEMM (128x128 tile, BK=32) ----------------
 * depth-3 pipeline, counted vmcnt, XOR bank-swizzle, XCD swizzle.
 * Used for mix (mode 2) and ffn-down (mode 3).                          */
__global__ __launch_bounds__(256) void gemm_bf16(int aid, int bid, int Kp, int mode,
                                                 const float* __restrict__ ext,
                                                 float* __restrict__ eout) {
  __shared__ __align__(16) unsigned short Al[3][128 * 32];
  __shared__ __align__(16) unsigned short Bl[3][128 * 32];
  const unsigned short* A = bsel(aid);
  const unsigned short* Bt = bsel(bid);
  int tid = threadIdx.x;
  int nbx = gridDim.x;
  int nwg = nbx * gridDim.y;
  int lid = blockIdx.y * nbx + blockIdx.x;
  int cpx = nwg >> 3;
  int swzb = (lid & 7) * cpx + (lid >> 3);
  int m0 = (swzb / nbx) * 128, n0 = (swzb % nbx) * 128;
  int wave = tid >> 6, lane = tid & 63;
  int wm = (wave >> 1) * 64, wn = (wave & 1) * 64;
  int lrow = tid >> 2;
  int lcol = ((tid & 3) ^ ((lrow >> 1) & 3)) * 8;
  f32x4 acc[4][4] = {};
  const int l15 = lane & 15, lg = lane >> 4;
  const int sw = (lg ^ ((l15 >> 1) & 3)) * 8;
  const int nt = Kp >> 5;
  const unsigned short* Arow = A + (size_t)m0 * Kp;
  const unsigned short* Brow = Bt + (size_t)n0 * Kp;
  {
    GLDS_(Arow + (size_t)lrow * Kp + lcol,        Al[0] + wave * 512);
    GLDS_(Arow + (size_t)(64 + lrow) * Kp + lcol, Al[0] + 2048 + wave * 512);
    GLDS_(Brow + (size_t)lrow * Kp + lcol,        Bl[0] + wave * 512);
    GLDS_(Brow + (size_t)(64 + lrow) * Kp + lcol, Bl[0] + 2048 + wave * 512);
    GLDS_(Arow + (size_t)lrow * Kp + 32 + lcol,        Al[1] + wave * 512);
    GLDS_(Arow + (size_t)(64 + lrow) * Kp + 32 + lcol, Al[1] + 2048 + wave * 512);
    GLDS_(Brow + (size_t)lrow * Kp + 32 + lcol,        Bl[1] + wave * 512);
    GLDS_(Brow + (size_t)(64 + lrow) * Kp + 32 + lcol, Bl[1] + 2048 + wave * 512);
  }
  int c0i = 0, c1i = 1, c2i = 2;
  for (int t = 0; t < nt; t++) {
    if (t + 2 < nt) {
      int k0 = (t + 2) << 5;
      GLDS_(Arow + (size_t)lrow * Kp + k0 + lcol,        Al[c2i] + wave * 512);
      GLDS_(Arow + (size_t)(64 + lrow) * Kp + k0 + lcol, Al[c2i] + 2048 + wave * 512);
      GLDS_(Brow + (size_t)lrow * Kp + k0 + lcol,        Bl[c2i] + wave * 512);
      GLDS_(Brow + (size_t)(64 + lrow) * Kp + k0 + lcol, Bl[c2i] + 2048 + wave * 512);
      asm volatile("s_waitcnt vmcnt(8)" ::: "memory");
    } else if (t + 1 < nt) {
      asm volatile("s_waitcnt vmcnt(4)" ::: "memory");
    } else {
      asm volatile("s_waitcnt vmcnt(0)" ::: "memory");
    }
    __builtin_amdgcn_sched_barrier(0);
    __builtin_amdgcn_s_barrier();
    __builtin_amdgcn_sched_barrier(0);
    bf16x8 af[4], bf[4];
    #pragma unroll
    for (int i = 0; i < 4; i++)
      af[i] = *(const bf16x8*)&Al[c0i][(wm + i * 16 + l15) * 32 + sw];
    #pragma unroll
    for (int j = 0; j < 4; j++)
      bf[j] = *(const bf16x8*)&Bl[c0i][(wn + j * 16 + l15) * 32 + sw];
    #pragma unroll
    for (int i = 0; i < 4; i++)
      #pragma unroll
      for (int j = 0; j < 4; j++)
        acc[i][j] = MFMA_(af[i], bf[j], acc[i][j]);
    __builtin_amdgcn_sched_barrier(0);
    __builtin_amdgcn_s_barrier();
    __builtin_amdgcn_sched_barrier(0);
    int tmp = c0i; c0i = c1i; c1i = c2i; c2i = tmp;
  }
  int C0 = n0 + wn;
  if (mode == 2) {                       /* f_h = ext + acc */
    #pragma unroll
    for (int i = 0; i < 4; i++) {
      int r0i = m0 + wm + i * 16 + lg * 4;
      #pragma unroll
      for (int j = 0; j < 4; j++)
        #pragma unroll
        for (int r = 0; r < 4; r++) {
          size_t off = (size_t)(r0i + r) * D_ + C0 + j * 16 + l15;
          f_h[off] = ext[off] + acc[i][j][r];
        }
    }
  } else {                               /* eout = f_h + acc */
    #pragma unroll
    for (int i = 0; i < 4; i++) {
      int r0i = m0 + wm + i * 16 + lg * 4;
      #pragma unroll
      for (int j = 0; j < 4; j++)
        #pragma unroll
        for (int r = 0; r < 4; r++) {
          size_t off = (size_t)(r0i + r) * D_ + C0 + j * 16 + l15;
          eout[off] = f_h[off] + acc[i][j][r];
        }
    }
  }
}

/* ================= chunked WY delta rule, linear-recurrence form ================= */

__global__ __launch_bounds__(256) void prep_k() {
  __shared__ __align__(16) char sm[40448];
  unsigned short* sKT = (unsigned short*)sm;             /* [64][80] K^T; Kd in place later */
  unsigned short* sVT = (unsigned short*)(sm + 10240);   /* [64][80] (beta*V)^T; Z^T in place later */
  unsigned short* sAb = (unsigned short*)(sm + 20480);   /* [64][72] bf16 Ab */
  unsigned short* sXbS = (unsigned short*)(sm + 20480);  /* overlay: pre-scaled Tinv (after P4) */
  unsigned short* sYT = (unsigned short*)(sm + 20480);   /* overlay after P5 */
  unsigned short* sXb = (unsigned short*)(sm + 29696);   /* [64][72] bf16 Tinv */
  float* sL  = (float*)(sm + 38912);
  float* sB  = (float*)(sm + 39168);
  float* sS2 = (float*)(sm + 39424);
  float* sDec= (float*)(sm + 39680);
  float* sGC = (float*)(sm + 39936);

  int gid = blockIdx.x;
  int ch = gid & 31, bh = gid >> 5;
  int b = bh >> 4, h = bh & 15;
  int c0 = ch * 64, hb = h * HD_;
  int rowb = b * T_ + c0;
  int tid = threadIdx.x;
  int w = tid >> 6, lane = tid & 63, l15 = lane & 15, lg = lane >> 4;
  size_t g4 = (size_t)gid * 4096;

  /* P1: decay prefix + row scalars (wave 0) */
  if (tid < 64) {
    size_t rb = ((size_t)(rowb + tid)) * H_ + h;
    float la = log2f(f_al[rb]);
    #pragma unroll
    for (int m = 1; m < 64; m <<= 1) {
      float o = __shfl_up(la, m);
      if (tid >= m) la += o;
    }
    float L63 = __shfl(la, 63);
    float bt = f_be[rb];
    float g = exp2f(la);
    sL[tid] = la; sB[tid] = bt; sS2[tid] = bt * g;
    sDec[tid] = exp2f(L63 - la);
    if (tid == 63) sGC[0] = g;
    g_rs[(size_t)gid*256 + tid*4 + 0] = bt;
    g_rs[(size_t)gid*256 + tid*4 + 1] = bt * g;
    g_rs[(size_t)gid*256 + tid*4 + 2] = g;
  }
  __syncthreads();

  /* P2: packed-u32 staging of K^T and (beta*V)^T */
  {
    int tp = tid >> 3, q8 = tid & 7;
    int t0 = 2 * tp, t1 = 2 * tp + 1;
    const bf16x8 k0 = *(const bf16x8*)(b_k + (size_t)(rowb + t0) * D_ + hb + q8 * 8);
    const bf16x8 k1 = *(const bf16x8*)(b_k + (size_t)(rowb + t1) * D_ + hb + q8 * 8);
    const bf16x8 v0 = *(const bf16x8*)(b_v + (size_t)(rowb + t0) * D_ + hb + q8 * 8);
    const bf16x8 v1 = *(const bf16x8*)(b_v + (size_t)(rowb + t1) * D_ + hb + q8 * 8);
    float s0 = sB[t0], s1v = sB[t1];
    unsigned* KT32 = (unsigned*)sKT;
    unsigned* VT32 = (unsigned*)sVT;
    #pragma unroll
    for (int i = 0; i < 8; i++) {
      int k = q8 * 8 + i;
      KT32[k*40 + tp] = (unsigned)(unsigned short)k0[i] |
                        ((unsigned)(unsigned short)k1[i] << 16);
      unsigned lo = f2b(b2f((unsigned short)v0[i]) * s0);
      unsigned hi = f2b(b2f((unsigned short)v1[i]) * s1v);
      VT32[k*40 + tp] = lo | (hi << 16);
    }
  }
  /* P3: KK^T, QK^T -> sAb + g_Gqk */
  {
    bf16x8 bK[2], aK[4][2], aQ[4][2];
    #pragma unroll
    for (int k2 = 0; k2 < 2; k2++) {
      bK[k2] = *(const bf16x8*)&b_k[(size_t)(rowb + w*16 + l15)*D_ + hb + k2*32 + lg*8];
      #pragma unroll
      for (int ti = 0; ti < 4; ti++) {
        aK[ti][k2] = *(const bf16x8*)&b_k[(size_t)(rowb + ti*16 + l15)*D_ + hb + k2*32 + lg*8];
        aQ[ti][k2] = *(const bf16x8*)&b_q[(size_t)(rowb + ti*16 + l15)*D_ + hb + k2*32 + lg*8];
      }
    }
    f32x4 ck[4] = {}, cq[4] = {};
    #pragma unroll
    for (int k2 = 0; k2 < 2; k2++)
      #pragma unroll
      for (int ti = 0; ti < 4; ti++) {
        ck[ti] = MFMA_(aK[ti][k2], bK[k2], ck[ti]);
        cq[ti] = MFMA_(aQ[ti][k2], bK[k2], cq[ti]);
      }
    int j = w*16 + l15;
    float Lj = sL[j];
    #pragma unroll
    for (int ti = 0; ti < 4; ti++)
      #pragma unroll
      for (int r = 0; r < 4; r++) {
        int t = ti*16 + lg*4 + r;
        float ratio = exp2f(sL[t] - Lj);
        sAb[t*72 + j] = f2b((j < t) ? sB[t] * ratio * ck[ti][r] : 0.f);
        g_Gqk[g4 + t*64 + j] = f2b((j <= t) ? ratio * cq[ti][r] : 0.f);
      }
  }
  __syncthreads();
  /* P4: invert (I+Ab) -> sXb bf16 (+ pre-scaled copy sXbS over sAb);
     register-resident, quad-blocked */
  {
    int c = (w << 4) + (lane >> 2);
    int p = lane & 3;
    int rb16 = p << 4;
    float xr[16];
    #pragma unroll
    for (int j = 0; j < 16; j++) xr[j] = 0.f;
    #pragma unroll
    for (int q = 0; q < 16; q++) {
      int r0 = 4 * q;
      const unsigned short* abr = sAb + r0 * 72 + rb16;
      bf16x8 A0a = *(const bf16x8*)(abr);
      bf16x8 A0b = *(const bf16x8*)(abr + 8);
      bf16x8 A1a = *(const bf16x8*)(abr + 72);
      bf16x8 A1b = *(const bf16x8*)(abr + 80);
      bf16x8 A2a = *(const bf16x8*)(abr + 144);
      bf16x8 A2b = *(const bf16x8*)(abr + 152);
      bf16x8 A3a = *(const bf16x8*)(abr + 216);
      bf16x8 A3b = *(const bf16x8*)(abr + 224);
      float s0 = 0.f, s1 = 0.f, s2 = 0.f, s3 = 0.f;
      #pragma unroll
      for (int j = 0; j < 8; j++) {
        float xv = xr[j], xw = xr[8 + j];
        s0 = fmaf(b2f((unsigned short)A0a[j]), xv, s0);
        s1 = fmaf(b2f((unsigned short)A1a[j]), xv, s1);
        s2 = fmaf(b2f((unsigned short)A2a[j]), xv, s2);
        s3 = fmaf(b2f((unsigned short)A3a[j]), xv, s3);
        s0 = fmaf(b2f((unsigned short)A0b[j]), xw, s0);
        s1 = fmaf(b2f((unsigned short)A1b[j]), xw, s1);
        s2 = fmaf(b2f((unsigned short)A2b[j]), xw, s2);
        s3 = fmaf(b2f((unsigned short)A3b[j]), xw, s3);
      }
      s0 += __shfl_xor(s0, 1); s0 += __shfl_xor(s0, 2);
      s1 += __shfl_xor(s1, 1); s1 += __shfl_xor(s1, 2);
      s2 += __shfl_xor(s2, 1); s2 += __shfl_xor(s2, 2);
      s3 += __shfl_xor(s3, 1); s3 += __shfl_xor(s3, 2);
      float a10 = b2f(sAb[(r0+1)*72 + r0]);
      float a20 = b2f(sAb[(r0+2)*72 + r0]);
      float a21 = b2f(sAb[(r0+2)*72 + r0+1]);
      float a30 = b2f(sAb[(r0+3)*72 + r0]);
      float a31 = b2f(sAb[(r0+3)*72 + r0+1]);
      float a32 = b2f(sAb[(r0+3)*72 + r0+2]);
      float x0 = ((r0+0) == c ? 1.f : 0.f) - s0;
      float x1 = ((r0+1) == c ? 1.f : 0.f) - s1 - a10*x0;
      float x2 = ((r0+2) == c ? 1.f : 0.f) - s2 - a20*x0 - a21*x1;
      float x3 = ((r0+3) == c ? 1.f : 0.f) - s3 - a30*x0 - a31*x1 - a32*x2;
      if (p == (q >> 2)) {
        int ji = 4 * (q & 3);
        xr[ji+0] = x0; xr[ji+1] = x1; xr[ji+2] = x2; xr[ji+3] = x3;
      }
    }
    #pragma unroll
    for (int j = 0; j < 16; j++)
      sXb[(rb16 + j)*72 + c] = f2b(xr[j]);
    __syncthreads();                       /* all waves done reading sAb */
    float s2c = sS2[c];
    #pragma unroll
    for (int j = 0; j < 16; j++)
      sXbS[(rb16 + j)*72 + c] = f2b(xr[j] * s2c);
  }
  __syncthreads();
  /* P5: Y^T (regs), Y -> g_Y, Z^T (regs + g_ZT); scaled Tinv via sXbS (b128) */
  int m0 = w * 16;
  f32x4 cyT[4], cz[4];
  {
    bf16x8 aKT[2];
    aKT[0] = *(const bf16x8*)&sKT[(m0 + l15)*80 + lg*8];
    aKT[1] = *(const bf16x8*)&sKT[(m0 + l15)*80 + 32 + lg*8];
    #pragma unroll
    for (int n = 0; n < 4; n++) {
      cyT[n] = f32x4{0.f, 0.f, 0.f, 0.f};
      #pragma unroll
      for (int k2 = 0; k2 < 2; k2++) {
        bf16x8 bb = *(const bf16x8*)&sXbS[(n*16 + l15)*72 + k2*32 + lg*8];
        cyT[n] = MFMA_(aKT[k2], bb, cyT[n]);
      }
    }
    bf16x8 aT2[2];
    aT2[0] = *(const bf16x8*)&sXbS[(m0 + l15)*72 + lg*8];
    aT2[1] = *(const bf16x8*)&sXbS[(m0 + l15)*72 + 32 + lg*8];
    #pragma unroll
    for (int n = 0; n < 4; n++) {
      f32x4 c = {};
      #pragma unroll
      for (int k2 = 0; k2 < 2; k2++) {
        bf16x8 bKT = *(const bf16x8*)&sKT[(n*16 + l15)*80 + k2*32 + lg*8];
        c = MFMA_(aT2[k2], bKT, c);
      }
      #pragma unroll
      for (int r = 0; r < 4; r++)
        g_Y[g4 + (m0 + lg*4 + r)*64 + n*16 + l15] = f2b(c[r]);
    }
    bf16x8 aV[2];
    aV[0] = *(const bf16x8*)&sVT[(m0 + l15)*80 + lg*8];
    aV[1] = *(const bf16x8*)&sVT[(m0 + l15)*80 + 32 + lg*8];
    #pragma unroll
    for (int n = 0; n < 4; n++) {
      cz[n] = f32x4{0.f, 0.f, 0.f, 0.f};
      #pragma unroll
      for (int k2 = 0; k2 < 2; k2++) {
        bf16x8 bT = *(const bf16x8*)&sXb[(n*16 + l15)*72 + k2*32 + lg*8];
        cz[n] = MFMA_(aV[k2], bT, cz[n]);
      }
      #pragma unroll
      for (int r = 0; r < 4; r++)
        g_ZT[g4 + (m0 + lg*4 + r)*64 + n*16 + l15] = f2b(cz[n][r]);
    }
  }
  __syncthreads();
  /* P6: write Y^T (over sXbS) + Z^T in place; P7: Kd = K^T*dec in place */
  #pragma unroll
  for (int n = 0; n < 4; n++)
    #pragma unroll
    for (int r = 0; r < 4; r++) {
      sYT[(m0 + lg*4 + r)*72 + n*16 + l15] = f2b(cyT[n][r]);
      sVT[(m0 + lg*4 + r)*80 + n*16 + l15] = f2b(cz[n][r]);
    }
  {
    int xx = tid >> 2, q = tid & 3;
    bf16x8 v0 = *(const bf16x8*)&sKT[xx*80 + q*16];
    bf16x8 v1 = *(const bf16x8*)&sKT[xx*80 + q*16 + 8];
    bf16x8 d0, d1;
    #pragma unroll
    for (int i = 0; i < 8; i++) {
      d0[i] = (short)f2b(b2f((unsigned short)v0[i]) * sDec[q*16 + i]);
      d1[i] = (short)f2b(b2f((unsigned short)v1[i]) * sDec[q*16 + 8 + i]);
    }
    *(bf16x8*)&sKT[xx*80 + q*16] = d0;
    *(bf16x8*)&sKT[xx*80 + q*16 + 8] = d1;
  }
  __syncthreads();
  /* P8: A = gC I - Kd*Y ; Bm^T = (Kd*Z)^T */
  {
    float gC = sGC[0];
    bf16x8 aKd[2];
    aKd[0] = *(const bf16x8*)&sKT[(m0 + l15)*80 + lg*8];
    aKd[1] = *(const bf16x8*)&sKT[(m0 + l15)*80 + 32 + lg*8];
    #pragma unroll
    for (int n = 0; n < 4; n++) {
      f32x4 c = {};
      #pragma unroll
      for (int k2 = 0; k2 < 2; k2++) {
        bf16x8 bY = *(const bf16x8*)&sYT[(n*16 + l15)*72 + k2*32 + lg*8];
        c = MFMA_(aKd[k2], bY, c);
      }
      #pragma unroll
      for (int r = 0; r < 4; r++) {
        int row = m0 + lg*4 + r, col = n*16 + l15;
        g_A[g4 + row*64 + col] = f2b(((row == col) ? gC : 0.f) - c[r]);
      }
    }
    #pragma unroll
    for (int n = 0; n < 4; n++) {
      f32x4 c = {};
      #pragma unroll
      for (int k2 = 0; k2 < 2; k2++) {
        bf16x8 bZ = *(const bf16x8*)&sVT[(n*16 + l15)*80 + k2*32 + lg*8];
        c = MFMA_(aKd[k2], bZ, c);
      }
      *(f32x4*)&g_BmT[g4 + (size_t)(n*16 + l15)*64 + m0 + lg*4] = c;
    }
  }
}

/* ---- seq: S' = A S + Bm per chunk; wave = v-strip, barrier-free ---- */
__global__ __launch_bounds__(256) void seq_k() {
  __shared__ __align__(16) unsigned short sST[4][16*80];
  int bh = blockIdx.x;
  int tid = threadIdx.x, w = tid >> 6, lane = tid & 63;
  int l15 = lane & 15, lg = lane >> 4;
  unsigned short* st = sST[w];
  for (int i = lane; i < 16*80; i += 64) st[i] = 0;
  f32x4 cerr[4] = {};
  bf16x8 aA[4][2];
  f32x4 cini[4];
  size_t g40 = (size_t)(bh * 32) * 4096;
  #pragma unroll
  for (int m = 0; m < 4; m++) {
    aA[m][0] = *(const bf16x8*)&g_A[g40 + (m*16 + l15)*64 + lg*8];
    aA[m][1] = *(const bf16x8*)&g_A[g40 + (m*16 + l15)*64 + 32 + lg*8];
    cini[m] = *(const f32x4*)&g_BmT[g40 + (w*16 + l15)*64 + m*16 + lg*4];
  }
  for (int ch = 0; ch < NCH_; ch++) {
    size_t gid = (size_t)bh * 32 + ch;
    float gC = g_rs[gid*256 + 254];
    bf16x8 bS0 = *(const bf16x8*)&st[l15*80 + lg*8];
    bf16x8 bS1 = *(const bf16x8*)&st[l15*80 + 32 + lg*8];
    *(bf16x8*)&g_S[gid*4096 + (w*16 + l15)*64 + lg*8] = bS0;
    *(bf16x8*)&g_S[gid*4096 + (w*16 + l15)*64 + 32 + lg*8] = bS1;
    bf16x8 aAn[4][2];
    f32x4 cin2[4];
    if (ch + 1 < NCH_) {
      size_t g4n = (gid + 1) * 4096;
      #pragma unroll
      for (int m = 0; m < 4; m++) {
        aAn[m][0] = *(const bf16x8*)&g_A[g4n + (m*16 + l15)*64 + lg*8];
        aAn[m][1] = *(const bf16x8*)&g_A[g4n + (m*16 + l15)*64 + 32 + lg*8];
        cin2[m] = *(const f32x4*)&g_BmT[g4n + (w*16 + l15)*64 + m*16 + lg*4];
      }
    }
    f32x4 c[4];
    #pragma unroll
    for (int m = 0; m < 4; m++) {
      #pragma unroll
      for (int r = 0; r < 4; r++)
        c[m][r] = cini[m][r] + gC * cerr[m][r];
      c[m] = MFMA_(aA[m][0], bS0, c[m]);
      c[m] = MFMA_(aA[m][1], bS1, c[m]);
    }
    #pragma unroll
    for (int m = 0; m < 4; m++)
      #pragma unroll
      for (int r = 0; r < 4; r++) {
        float x = c[m][r];
        unsigned short q = f2b(x);
        cerr[m][r] = x - b2f(q);
        st[l15*80 + m*16 + lg*4 + r] = q;
      }
    if (ch + 1 < NCH_) {
      #pragma unroll
      for (int m = 0; m < 4; m++) {
        aA[m][0] = aAn[m][0]; aA[m][1] = aAn[m][1];
        cini[m] = cin2[m];
      }
    }
  }
}

/* ---- apply: U^T = Z^T - S^T Y^T ; O^T = gam (QS)^T + (Gqk U)^T ---- */
__global__ __launch_bounds__(256) void apply_k() {
  __shared__ __align__(16) unsigned short sUT[4][16*80];
  int gid = blockIdx.x;
  int ch = gid & 31, bh = gid >> 5;
  int b = bh >> 4, h = bh & 15;
  int c0 = ch * 64, hb = h * HD_;
  int rowb = b * T_ + c0;
  int tid = threadIdx.x, w = tid >> 6, lane = tid & 63;
  int l15 = lane & 15, lg = lane >> 4;
  unsigned short* ut = sUT[w];
  size_t g4 = (size_t)gid * 4096;
  bf16x8 aS[2];
  aS[0] = *(const bf16x8*)&g_S[g4 + (w*16 + l15)*64 + lg*8];
  aS[1] = *(const bf16x8*)&g_S[g4 + (w*16 + l15)*64 + 32 + lg*8];
  f32x4 cu[4];
  #pragma unroll
  for (int n = 0; n < 4; n++) {
    cu[n] = f32x4{0.f, 0.f, 0.f, 0.f};
    #pragma unroll
    for (int k2 = 0; k2 < 2; k2++) {
      bf16x8 bY = *(const bf16x8*)&g_Y[g4 + (n*16 + l15)*64 + k2*32 + lg*8];
      cu[n] = MFMA_(aS[k2], bY, cu[n]);
    }
  }
  #pragma unroll
  for (int n = 0; n < 4; n++)
    #pragma unroll
    for (int r = 0; r < 4; r++) {
      float zt = b2f(g_ZT[g4 + (w*16 + lg*4 + r)*64 + n*16 + l15]);
      ut[(lg*4 + r)*80 + n*16 + l15] = f2b(zt - cu[n][r]);
    }
  bf16x8 aU[2];
  aU[0] = *(const bf16x8*)&ut[l15*80 + lg*8];
  aU[1] = *(const bf16x8*)&ut[l15*80 + 32 + lg*8];
  f32x4 co[4];
  #pragma unroll
  for (int n = 0; n < 4; n++) {
    co[n] = f32x4{0.f, 0.f, 0.f, 0.f};
    #pragma unroll
    for (int k2 = 0; k2 < 2; k2++) {
      bf16x8 bQ = *(const bf16x8*)&b_q[(size_t)(rowb + n*16 + l15)*D_ + hb + k2*32 + lg*8];
      co[n] = MFMA_(aS[k2], bQ, co[n]);
    }
    float gm = g_rs[(size_t)gid*256 + (n*16 + l15)*4 + 2];
    #pragma unroll
    for (int r = 0; r < 4; r++) co[n][r] *= gm;
    #pragma unroll
    for (int k2 = 0; k2 < 2; k2++) {
      bf16x8 bG = *(const bf16x8*)&g_Gqk[g4 + (n*16 + l15)*64 + k2*32 + lg*8];
      co[n] = MFMA_(aU[k2], bG, co[n]);
    }
    ushort4 pk;
    pk.x = f2b(co[n][0]); pk.y = f2b(co[n][1]);
    pk.z = f2b(co[n][2]); pk.w = f2b(co[n][3]);
    *(ushort4*)&b_o[(size_t)(rowb + n*16 + l15)*D_ + hb + w*16 + lg*4] = pk;
  }
}

extern "C" void kernel_launch(void* const* d_in, const int* in_sizes, int n_in,
                              void* d_out, int out_size, void* d_ws, size_t ws_size,
                              hipStream_t stream) {
  const float* x   = (const float*)d_in[0];
  const float* n1w = (const float*)d_in[1];
  const float* n2w = (const float*)d_in[2];
  const float* cw  = (const float*)d_in[3];
  const float* cb  = (const float*)d_in[4];
  const float* wq  = (const float*)d_in[5];
  const float* wk  = (const float*)d_in[6];
  const float* wv  = (const float*)d_in[7];
  const float* wb  = (const float*)d_in[8];
  const float* wa  = (const float*)d_in[9];
  const float* wo  = (const float*)d_in[10];
  const float* wg  = (const float*)d_in[11];
  const float* wu  = (const float*)d_in[12];
  const float* wd  = (const float*)d_in[13];
  float* out = (float*)d_out;

  /* weight preprocessing */
  castTqkv_k<<<dim3(52, 16), 256, 0, stream>>>(wq, wk, wv, wb, wa);
  castT_k<<<dim3(16, 16), 256, 0, stream>>>(wo, D_, D_, 5, D_);
  castTgu_k<<<dim3(88, 16), 256, 0, stream>>>(wg, wu);
  castT_k<<<dim3(16, 44), 256, 0, stream>>>(wd, I_, D_, 7, IP_);

  /* norm1 scale + fused norm/conv/silu */
  rmssc_k<<<BT_, 256, 0, stream>>>(x);
  conv2_k<<<ND_ / 256, 256, 0, stream>>>(x, cw, cb, n1w);

  /* fused QKV+gates GEMM, 256x256 8-wave BK=64 4-phase v2 (early staging) */
  gemm256<<<dim3(13, 16), 512, 0, stream>>>(0, 4, D_, 0);

  /* chunked WY delta rule: parallel prep, tiny serial scan, parallel apply */
  prep_k<<<NG_, 256, 0, stream>>>();
  seq_k<<<32, 256, 0, stream>>>();
  apply_k<<<NG_, 256, 0, stream>>>();

  /* mix = o@wo + x -> f_h (128^2 kernel) */
  gemm_bf16<<<dim3(8, 32), 256, 0, stream>>>(1, 5, D_, 2, x, nullptr);
  /* hn = rmsnorm(h) -> b_hn */
  rms2_k<<<BT_, 256, 0, stream>>>(n2w);
  /* g,u fused GEMM + swiglu, 256x256 8-wave BK=64 4-phase v2 -> b_f */
  gemm256<<<dim3(22, 16), 512, 0, stream>>>(2, 6, D_, 1);
  /* ffn = f@wd + h -> out (128^2 kernel) */
  gemm_bf16<<<dim3(8, 32), 256, 0, stream>>>(3, 7, IP_, 3, nullptr, out);
}

// Round 21
// 416.004 us; speedup vs baseline: 1.0047x; 1.0047x over previous
//
#include <hip/hip_runtime.h>
#include <math.h>

#define D_ 1024
#define H_ 16
#define HD_ 64
#define KW_ 4
#define I_ 2764
#define IP_ 2816              /* I padded to 22*128 */
#define NQKV_ 3328            /* q|k|v|gates fused N, padded to 13*256 */
#define NGU_ 5632             /* interleaved g/u N, 22*256 */
#define B_ 2
#define T_ 2048
#define BT_ (B_*T_)           /* 4096 */
#define ND_ (BT_*D_)          /* 4194304 */
#define NH_ (BT_*H_)          /* 65536 */
#define NCH_ 32               /* chunks per sequence (T/64) */
#define NG_ (32*NCH_)         /* 1024 (bh,chunk) groups */
#define EPS_ 1e-6f
#define GATE_BIAS_ 4.0f

typedef __attribute__((ext_vector_type(8))) short bf16x8;
typedef __attribute__((ext_vector_type(4))) float f32x4;

#define MFMA_(a,b,c) __builtin_amdgcn_mfma_f32_16x16x32_bf16(a, b, c, 0, 0, 0)
#define GLDS_(src, dst) __builtin_amdgcn_global_load_lds( \
    (const __attribute__((address_space(1))) void*)(src), \
    (__attribute__((address_space(3))) void*)(dst), 16, 0, 0)

/* ---------------- static buffers ---------------- */
__device__ float f_sc1[BT_];
__device__ float f_be[NH_];
__device__ float f_al[NH_];
__device__ float f_h[ND_];
__device__ float g_rs[NG_ * 256];
__device__ float g_BmT[(size_t)NG_*4096];            /* Bm^T [v][k'] f32 */
__device__ unsigned short g_Gqk[(size_t)NG_*4096];   /* [t][t'] */
__device__ unsigned short g_Y[(size_t)NG_*4096];     /* Y [t][k] */
__device__ unsigned short g_ZT[(size_t)NG_*4096];    /* Z^T [v][t] */
__device__ unsigned short g_A[(size_t)NG_*4096];     /* A [k'][k] */
__device__ unsigned short g_S[(size_t)NG_*4096];     /* entering S^T [v][k] */
__device__ unsigned short b_q[ND_];
__device__ unsigned short b_k[ND_];
__device__ unsigned short b_v[ND_];
__device__ unsigned short b_xc[ND_];
__device__ unsigned short b_o[ND_];
__device__ unsigned short b_hn[ND_];
__device__ unsigned short b_f[(size_t)BT_*IP_];
__device__ unsigned short b_wqkvT[(size_t)NQKV_*D_];
__device__ unsigned short b_woT[D_*D_];
__device__ unsigned short b_wguT[(size_t)NGU_*D_];
__device__ unsigned short b_wdT[(size_t)D_*IP_];

__device__ __forceinline__ unsigned short f2b(float x) {
  union { float f; unsigned u; } a; a.f = x;
  unsigned r = a.u + 0x7fff + ((a.u >> 16) & 1);
  return (unsigned short)(r >> 16);
}
__device__ __forceinline__ float b2f(unsigned short s) {
  union { unsigned u; float f; } a; a.u = ((unsigned)s) << 16; return a.f;
}

__device__ __forceinline__ const unsigned short* bsel(int id) {
  switch (id) {
    case 0: return b_xc;  case 1: return b_o;    case 2: return b_hn;
    case 3: return b_f;   case 4: return b_wqkvT; case 5: return b_woT;
    case 6: return b_wguT; default: return b_wdT;
  }
}
__device__ __forceinline__ unsigned short* bselw(int id) {
  return (unsigned short*)bsel(id);
}

/* ---------------- RMSNorm-1 scale only: f_sc1[row] ---------------- */
__global__ __launch_bounds__(256) void rmssc_k(const float* __restrict__ x) {
  int row = blockIdx.x;
  int tid = threadIdx.x;
  float4 v = ((const float4*)(x + (size_t)row * D_))[tid];
  float ss = v.x*v.x + v.y*v.y + v.z*v.z + v.w*v.w;
  #pragma unroll
  for (int o = 32; o > 0; o >>= 1) ss += __shfl_down(ss, o);
  __shared__ float sred[4];
  if ((tid & 63) == 0) sred[tid >> 6] = ss;
  __syncthreads();
  if (tid == 0)
    f_sc1[row] = rsqrtf((sred[0]+sred[1]+sred[2]+sred[3]) / (float)D_ + EPS_);
}

/* ---------------- RMSNorm 2 -> bf16 b_hn ---------------- */
__global__ __launch_bounds__(256) void rms2_k(const float* __restrict__ w) {
  int row = blockIdx.x;
  const float* xr = f_h + (size_t)row * D_;
  int tid = threadIdx.x;
  float4 v = ((const float4*)xr)[tid];
  float ss = v.x*v.x + v.y*v.y + v.z*v.z + v.w*v.w;
  #pragma unroll
  for (int o = 32; o > 0; o >>= 1) ss += __shfl_down(ss, o);
  __shared__ float sred[4];
  __shared__ float sscale;
  if ((tid & 63) == 0) sred[tid >> 6] = ss;
  __syncthreads();
  if (tid == 0)
    sscale = rsqrtf((sred[0]+sred[1]+sred[2]+sred[3]) / (float)D_ + EPS_);
  __syncthreads();
  float s = sscale;
  float4 wv = ((const float4*)w)[tid];
  unsigned short* orow = b_hn + (size_t)row * D_ + tid * 4;
  orow[0] = f2b(v.x*s*wv.x); orow[1] = f2b(v.y*s*wv.y);
  orow[2] = f2b(v.z*s*wv.z); orow[3] = f2b(v.w*s*wv.w);
}

/* ---------------- causal depthwise conv + inline rmsnorm + SiLU -> b_xc ---------------- */
__global__ __launch_bounds__(256) void conv2_k(const float* __restrict__ x,
                                               const float* __restrict__ cw,
                                               const float* __restrict__ cb,
                                               const float* __restrict__ n1w) {
  int idx = blockIdx.x * 256 + threadIdx.x;
  int d = idx & (D_ - 1);
  int bt = idx >> 10;
  int t = bt & (T_ - 1);
  float wd = n1w[d];
  float acc = cb[d];
  #pragma unroll
  for (int j = 0; j < KW_; j++) {
    int tt = t - (KW_ - 1) + j;
    if (tt >= 0) {
      int off = j - (KW_ - 1);
      acc += x[(size_t)idx + (size_t)off * D_] * f_sc1[bt + off] * wd * cw[d * KW_ + j];
    }
  }
  float s = acc / (1.f + expf(-acc));
  b_xc[idx] = f2b(s);
}

/* ---------------- fused QKV+gates weight cast+transpose ---------------- */
__global__ __launch_bounds__(256) void castTqkv_k(const float* __restrict__ wq,
                                                  const float* __restrict__ wk,
                                                  const float* __restrict__ wv,
                                                  const float* __restrict__ wb,
                                                  const float* __restrict__ wa) {
  __shared__ float s[64][65];
  int n0 = blockIdx.x * 64, k0 = blockIdx.y * 64;
  int tx = threadIdx.x & 63, ty = threadIdx.x >> 6;
  int nn = n0 + tx;
  const float* src = nullptr; int col = 0, ld = 1024;
  if (nn < 1024)      { src = wq; col = nn; }
  else if (nn < 2048) { src = wk; col = nn - 1024; }
  else if (nn < 3072) { src = wv; col = nn - 2048; }
  else if (nn < 3088) { src = wb; col = nn - 3072; ld = 16; }
  else if (nn < 3104) { src = wa; col = nn - 3088; ld = 16; }
  #pragma unroll
  for (int j = ty; j < 64; j += 4)
    s[j][tx] = src ? src[(size_t)(k0 + j) * ld + col] : 0.f;
  __syncthreads();
  #pragma unroll
  for (int j = ty; j < 64; j += 4)
    b_wqkvT[(size_t)(n0 + j) * D_ + k0 + tx] = f2b(s[tx][j]);
}

/* ---------------- interleaved G/U weight cast ---------------- */
__global__ __launch_bounds__(256) void castTgu_k(const float* __restrict__ wg,
                                                 const float* __restrict__ wu) {
  __shared__ float s[64][65];
  int n0 = blockIdx.x * 64, k0 = blockIdx.y * 64;
  int tx = threadIdx.x & 63, ty = threadIdx.x >> 6;
  int nn = n0 + tx;
  int inner = nn & 31;
  int col = (nn >> 5) * 16 + (inner & 15);
  const float* src = (inner < 16) ? wg : wu;
  bool ok = (col < I_);
  #pragma unroll
  for (int j = ty; j < 64; j += 4)
    s[j][tx] = ok ? src[(size_t)(k0 + j) * I_ + col] : 0.f;
  __syncthreads();
  #pragma unroll
  for (int j = ty; j < 64; j += 4)
    b_wguT[(size_t)(n0 + j) * D_ + k0 + tx] = f2b(s[tx][j]);
}

/* ---------------- plain weight cast+transpose ---------------- */
__global__ __launch_bounds__(256) void castT_k(const float* __restrict__ W,
                                               int K, int N, int outid, int Kp) {
  __shared__ float s[64][65];
  unsigned short* out = bselw(outid);
  int k0 = blockIdx.y * 64, n0 = blockIdx.x * 64;
  int tx = threadIdx.x & 63, ty = threadIdx.x >> 6;
  #pragma unroll
  for (int j = ty; j < 64; j += 4) {
    int kk = k0 + j, nn = n0 + tx;
    s[j][tx] = (kk < K && nn < N) ? W[(size_t)kk * N + nn] : 0.f;
  }
  __syncthreads();
  #pragma unroll
  for (int j = ty; j < 64; j += 4)
    out[(size_t)(n0 + j) * Kp + k0 + tx] = f2b(s[tx][j]);
}

/* ---------------- 256x256 8-wave GEMM, BK=64, 4-phase interleave v2 ----------------
 * Early staging (p0: all A of t+1, p1: all B), per-phase barrier+lgkmcnt+
 * setprio'd 16-MFMA cluster, boundary vmcnt(0) covered by 2-3 phases.
 * mode 0: QKV epilogue; mode 1: GU swiglu epilogue.                         */
__global__ __launch_bounds__(512) void gemm256(int aid, int bid, int Kp, int mode) {
  __shared__ __align__(16) unsigned short Al[2][256 * 64];
  __shared__ __align__(16) unsigned short Bl[2][256 * 64];
  const unsigned short* A = bsel(aid);
  const unsigned short* Bt = bsel(bid);
  int tid = threadIdx.x;
  int nbx = gridDim.x;
  int nwg = nbx * gridDim.y;
  int lid = blockIdx.y * nbx + blockIdx.x;
  int cpx = nwg >> 3;
  int swzb = (lid & 7) * cpx + (lid >> 3);
  int m0 = (swzb / nbx) * 256, n0 = (swzb % nbx) * 256;
  int w = tid >> 6, lane = tid & 63;
  int wm = (w >> 2) * 128, wn = (w & 3) * 64;
  const int l15 = lane & 15, lg = lane >> 4;
  int srow = tid >> 3;                       /* staging row-in-64 (0..63) */
  int scol = ((tid & 7) ^ (srow & 7)) * 8;   /* pre-swizzled source slot  */
  int ldsw = w * 512;                        /* wave-uniform dst offset   */
  const unsigned short* Arow = A + (size_t)m0 * Kp;
  const unsigned short* Brow = Bt + (size_t)n0 * Kp;
  int swz0 = ((0 + lg) ^ (l15 & 7)) * 8;     /* read slot, k-half 0 */
  int swz1 = ((4 + lg) ^ (l15 & 7)) * 8;     /* read slot, k-half 1 */
  f32x4 acc[8][4] = {};
  const int nt = Kp >> 6;
  /* prologue: stage tile 0 fully */
  #pragma unroll
  for (int i = 0; i < 4; i++) {
    GLDS_(Arow + (size_t)(i * 64 + srow) * Kp + scol, Al[0] + i * 4096 + ldsw);
    GLDS_(Brow + (size_t)(i * 64 + srow) * Kp + scol, Bl[0] + i * 4096 + ldsw);
  }
  asm volatile("s_waitcnt vmcnt(0)" ::: "memory");
  __builtin_amdgcn_s_barrier();
  for (int t = 0; t < nt; t++) {
    int cur = t & 1;
    int k0n = (t + 1) << 6;
    bool more = (t + 1 < nt);
    bf16x8 bf0[4], bf1[4];
    /* ---- phase 0: ds bf(8)+af pair0(4); stage A-half0+A-half1 of t+1 ---- */
    {
      #pragma unroll
      for (int j = 0; j < 4; j++) {
        bf0[j] = *(const bf16x8*)&Bl[cur][(wn + j * 16 + l15) * 64 + swz0];
        bf1[j] = *(const bf16x8*)&Bl[cur][(wn + j * 16 + l15) * 64 + swz1];
      }
      bf16x8 a0k0 = *(const bf16x8*)&Al[cur][(wm + 0 * 16 + l15) * 64 + swz0];
      bf16x8 a0k1 = *(const bf16x8*)&Al[cur][(wm + 0 * 16 + l15) * 64 + swz1];
      bf16x8 a1k0 = *(const bf16x8*)&Al[cur][(wm + 1 * 16 + l15) * 64 + swz0];
      bf16x8 a1k1 = *(const bf16x8*)&Al[cur][(wm + 1 * 16 + l15) * 64 + swz1];
      if (more) {
        GLDS_(Arow + (size_t)(0 * 64 + srow) * Kp + k0n + scol, Al[cur ^ 1] + 0 * 4096 + ldsw);
        GLDS_(Arow + (size_t)(1 * 64 + srow) * Kp + k0n + scol, Al[cur ^ 1] + 1 * 4096 + ldsw);
        GLDS_(Arow + (size_t)(2 * 64 + srow) * Kp + k0n + scol, Al[cur ^ 1] + 2 * 4096 + ldsw);
        GLDS_(Arow + (size_t)(3 * 64 + srow) * Kp + k0n + scol, Al[cur ^ 1] + 3 * 4096 + ldsw);
      }
      __builtin_amdgcn_sched_barrier(0);
      __builtin_amdgcn_s_barrier();
      asm volatile("s_waitcnt lgkmcnt(0)" ::: "memory");
      __builtin_amdgcn_sched_barrier(0);
      __builtin_amdgcn_s_setprio(1);
      #pragma unroll
      for (int j = 0; j < 4; j++) {
        acc[0][j] = MFMA_(a0k0, bf0[j], acc[0][j]);
        acc[0][j] = MFMA_(a0k1, bf1[j], acc[0][j]);
        acc[1][j] = MFMA_(a1k0, bf0[j], acc[1][j]);
        acc[1][j] = MFMA_(a1k1, bf1[j], acc[1][j]);
      }
      __builtin_amdgcn_s_setprio(0);
      __builtin_amdgcn_sched_barrier(0);
      __builtin_amdgcn_s_barrier();
      __builtin_amdgcn_sched_barrier(0);
    }
    /* ---- phases 1..3: ds af pair p; p1 stages B-half0+B-half1 ---- */
    #pragma unroll
    for (int p = 1; p < 4; p++) {
      bf16x8 a0k0 = *(const bf16x8*)&Al[cur][(wm + (2 * p) * 16 + l15) * 64 + swz0];
      bf16x8 a0k1 = *(const bf16x8*)&Al[cur][(wm + (2 * p) * 16 + l15) * 64 + swz1];
      bf16x8 a1k0 = *(const bf16x8*)&Al[cur][(wm + (2 * p + 1) * 16 + l15) * 64 + swz0];
      bf16x8 a1k1 = *(const bf16x8*)&Al[cur][(wm + (2 * p + 1) * 16 + l15) * 64 + swz1];
      if (more && p == 1) {
        GLDS_(Brow + (size_t)(0 * 64 + srow) * Kp + k0n + scol, Bl[cur ^ 1] + 0 * 4096 + ldsw);
        GLDS_(Brow + (size_t)(1 * 64 + srow) * Kp + k0n + scol, Bl[cur ^ 1] + 1 * 4096 + ldsw);
        GLDS_(Brow + (size_t)(2 * 64 + srow) * Kp + k0n + scol, Bl[cur ^ 1] + 2 * 4096 + ldsw);
        GLDS_(Brow + (size_t)(3 * 64 + srow) * Kp + k0n + scol, Bl[cur ^ 1] + 3 * 4096 + ldsw);
      }
      __builtin_amdgcn_sched_barrier(0);
      __builtin_amdgcn_s_barrier();
      asm volatile("s_waitcnt lgkmcnt(0)" ::: "memory");
      __builtin_amdgcn_sched_barrier(0);
      __builtin_amdgcn_s_setprio(1);
      #pragma unroll
      for (int j = 0; j < 4; j++) {
        acc[2 * p][j]     = MFMA_(a0k0, bf0[j], acc[2 * p][j]);
        acc[2 * p][j]     = MFMA_(a0k1, bf1[j], acc[2 * p][j]);
        acc[2 * p + 1][j] = MFMA_(a1k0, bf0[j], acc[2 * p + 1][j]);
        acc[2 * p + 1][j] = MFMA_(a1k1, bf1[j], acc[2 * p + 1][j]);
      }
      __builtin_amdgcn_s_setprio(0);
      __builtin_amdgcn_sched_barrier(0);
      if (p == 3 && more)
        asm volatile("s_waitcnt vmcnt(0)" ::: "memory");
      __builtin_amdgcn_s_barrier();
      __builtin_amdgcn_sched_barrier(0);
    }
  }
  int C0 = n0 + wn;
  if (mode == 0) {
    if (C0 < 2048) {                     /* q or k: per-head l2norm -> bf16 */
      unsigned short* dst = (C0 < 1024) ? b_q : b_k;
      int cbase = C0 & 1023;
      #pragma unroll
      for (int i = 0; i < 8; i++) {
        int r0i = m0 + wm + i * 16 + lg * 4;
        #pragma unroll
        for (int r = 0; r < 4; r++) {
          float ss = acc[i][0][r]*acc[i][0][r] + acc[i][1][r]*acc[i][1][r]
                   + acc[i][2][r]*acc[i][2][r] + acc[i][3][r]*acc[i][3][r];
          ss += __shfl_xor(ss, 1); ss += __shfl_xor(ss, 2);
          ss += __shfl_xor(ss, 4); ss += __shfl_xor(ss, 8);
          float sc = rsqrtf(ss + EPS_);
          #pragma unroll
          for (int j = 0; j < 4; j++)
            dst[(size_t)(r0i + r) * D_ + cbase + j * 16 + l15] = f2b(acc[i][j][r] * sc);
        }
      }
    } else if (C0 < 3072) {              /* v -> bf16 */
      int cbase = C0 & 1023;
      #pragma unroll
      for (int i = 0; i < 8; i++) {
        int r0i = m0 + wm + i * 16 + lg * 4;
        #pragma unroll
        for (int j = 0; j < 4; j++)
          #pragma unroll
          for (int r = 0; r < 4; r++)
            b_v[(size_t)(r0i + r) * D_ + cbase + j * 16 + l15] = f2b(acc[i][j][r]);
      }
    } else if (C0 == 3072) {             /* beta (j=0) / alpha (j=1); j=2,3 pad */
      #pragma unroll
      for (int i = 0; i < 8; i++) {
        int r0i = m0 + wm + i * 16 + lg * 4;
        #pragma unroll
        for (int r = 0; r < 4; r++) {
          float vb = acc[i][0][r];
          f_be[(size_t)(r0i + r) * H_ + l15] = 1.f / (1.f + expf(-vb));
          float va = acc[i][1][r] + GATE_BIAS_;
          f_al[(size_t)(r0i + r) * H_ + l15] = 1.f / (1.f + expf(-va));
        }
      }
    }                                    /* C0 > 3072: pad, skip */
  } else {                               /* mode 1: swiglu -> b_f */
    #pragma unroll
    for (int i = 0; i < 8; i++) {
      int r0i = m0 + wm + i * 16 + lg * 4;
      #pragma unroll
      for (int jp = 0; jp < 2; jp++) {
        int j = jp * 2;
        int Lbase = ((C0 + j * 16) >> 5) * 16;
        #pragma unroll
        for (int r = 0; r < 4; r++) {
          float g = acc[i][j][r], u = acc[i][j + 1][r];
          float sg = g / (1.f + expf(-g));
          b_f[(size_t)(r0i + r) * IP_ + Lbase + l15] = f2b(sg * u);
        }
      }
    }
  }
}

/* ---------------- bf16 MFMA GEMM (128x128 tile, BK=32) ----------------
 * depth-3 pipeline, counted vmcnt, XOR bank-swizzle, XCD swizzle.
 * Used for mix (mode 2) and ffn-down (mode 3).                          */
__global__ __launch_bounds__(256) void gemm_bf16(int aid, int bid, int Kp, int mode,
                                                 const float* __restrict__ ext,
                                                 float* __restrict__ eout) {
  __shared__ __align__(16) unsigned short Al[3][128 * 32];
  __shared__ __align__(16) unsigned short Bl[3][128 * 32];
  const unsigned short* A = bsel(aid);
  const unsigned short* Bt = bsel(bid);
  int tid = threadIdx.x;
  int nbx = gridDim.x;
  int nwg = nbx * gridDim.y;
  int lid = blockIdx.y * nbx + blockIdx.x;
  int cpx = nwg >> 3;
  int swzb = (lid & 7) * cpx + (lid >> 3);
  int m0 = (swzb / nbx) * 128, n0 = (swzb % nbx) * 128;
  int wave = tid >> 6, lane = tid & 63;
  int wm = (wave >> 1) * 64, wn = (wave & 1) * 64;
  int lrow = tid >> 2;
  int lcol = ((tid & 3) ^ ((lrow >> 1) & 3)) * 8;
  f32x4 acc[4][4] = {};
  const int l15 = lane & 15, lg = lane >> 4;
  const int sw = (lg ^ ((l15 >> 1) & 3)) * 8;
  const int nt = Kp >> 5;
  const unsigned short* Arow = A + (size_t)m0 * Kp;
  const unsigned short* Brow = Bt + (size_t)n0 * Kp;
  {
    GLDS_(Arow + (size_t)lrow * Kp + lcol,        Al[0] + wave * 512);
    GLDS_(Arow + (size_t)(64 + lrow) * Kp + lcol, Al[0] + 2048 + wave * 512);
    GLDS_(Brow + (size_t)lrow * Kp + lcol,        Bl[0] + wave * 512);
    GLDS_(Brow + (size_t)(64 + lrow) * Kp + lcol, Bl[0] + 2048 + wave * 512);
    GLDS_(Arow + (size_t)lrow * Kp + 32 + lcol,        Al[1] + wave * 512);
    GLDS_(Arow + (size_t)(64 + lrow) * Kp + 32 + lcol, Al[1] + 2048 + wave * 512);
    GLDS_(Brow + (size_t)lrow * Kp + 32 + lcol,        Bl[1] + wave * 512);
    GLDS_(Brow + (size_t)(64 + lrow) * Kp + 32 + lcol, Bl[1] + 2048 + wave * 512);
  }
  int c0i = 0, c1i = 1, c2i = 2;
  for (int t = 0; t < nt; t++) {
    if (t + 2 < nt) {
      int k0 = (t + 2) << 5;
      GLDS_(Arow + (size_t)lrow * Kp + k0 + lcol,        Al[c2i] + wave * 512);
      GLDS_(Arow + (size_t)(64 + lrow) * Kp + k0 + lcol, Al[c2i] + 2048 + wave * 512);
      GLDS_(Brow + (size_t)lrow * Kp + k0 + lcol,        Bl[c2i] + wave * 512);
      GLDS_(Brow + (size_t)(64 + lrow) * Kp + k0 + lcol, Bl[c2i] + 2048 + wave * 512);
      asm volatile("s_waitcnt vmcnt(8)" ::: "memory");
    } else if (t + 1 < nt) {
      asm volatile("s_waitcnt vmcnt(4)" ::: "memory");
    } else {
      asm volatile("s_waitcnt vmcnt(0)" ::: "memory");
    }
    __builtin_amdgcn_sched_barrier(0);
    __builtin_amdgcn_s_barrier();
    __builtin_amdgcn_sched_barrier(0);
    bf16x8 af[4], bf[4];
    #pragma unroll
    for (int i = 0; i < 4; i++)
      af[i] = *(const bf16x8*)&Al[c0i][(wm + i * 16 + l15) * 32 + sw];
    #pragma unroll
    for (int j = 0; j < 4; j++)
      bf[j] = *(const bf16x8*)&Bl[c0i][(wn + j * 16 + l15) * 32 + sw];
    #pragma unroll
    for (int i = 0; i < 4; i++)
      #pragma unroll
      for (int j = 0; j < 4; j++)
        acc[i][j] = MFMA_(af[i], bf[j], acc[i][j]);
    __builtin_amdgcn_sched_barrier(0);
    __builtin_amdgcn_s_barrier();
    __builtin_amdgcn_sched_barrier(0);
    int tmp = c0i; c0i = c1i; c1i = c2i; c2i = tmp;
  }
  int C0 = n0 + wn;
  if (mode == 2) {                       /* f_h = ext + acc */
    #pragma unroll
    for (int i = 0; i < 4; i++) {
      int r0i = m0 + wm + i * 16 + lg * 4;
      #pragma unroll
      for (int j = 0; j < 4; j++)
        #pragma unroll
        for (int r = 0; r < 4; r++) {
          size_t off = (size_t)(r0i + r) * D_ + C0 + j * 16 + l15;
          f_h[off] = ext[off] + acc[i][j][r];
        }
    }
  } else {                               /* eout = f_h + acc */
    #pragma unroll
    for (int i = 0; i < 4; i++) {
      int r0i = m0 + wm + i * 16 + lg * 4;
      #pragma unroll
      for (int j = 0; j < 4; j++)
        #pragma unroll
        for (int r = 0; r < 4; r++) {
          size_t off = (size_t)(r0i + r) * D_ + C0 + j * 16 + l15;
          eout[off] = f_h[off] + acc[i][j][r];
        }
    }
  }
}

/* ================= chunked WY delta rule, linear-recurrence form ================= */

__global__ __launch_bounds__(256) void prep_k() {
  __shared__ __align__(16) char sm[40448];
  unsigned short* sKT = (unsigned short*)sm;             /* [64][80] K^T; Kd in place later */
  unsigned short* sVT = (unsigned short*)(sm + 10240);   /* [64][80] (beta*V)^T; Z^T in place later */
  unsigned short* sAb = (unsigned short*)(sm + 20480);   /* [64][72] bf16 Ab */
  unsigned short* sYT = (unsigned short*)(sm + 20480);   /* overlay after P4 */
  unsigned short* sXb = (unsigned short*)(sm + 29696);   /* [64][72] bf16 Tinv */
  float* sL  = (float*)(sm + 38912);
  float* sB  = (float*)(sm + 39168);
  float* sS2 = (float*)(sm + 39424);
  float* sDec= (float*)(sm + 39680);
  float* sGC = (float*)(sm + 39936);

  int gid = blockIdx.x;
  int ch = gid & 31, bh = gid >> 5;
  int b = bh >> 4, h = bh & 15;
  int c0 = ch * 64, hb = h * HD_;
  int rowb = b * T_ + c0;
  int tid = threadIdx.x;
  int w = tid >> 6, lane = tid & 63, l15 = lane & 15, lg = lane >> 4;
  size_t g4 = (size_t)gid * 4096;

  /* P1: decay prefix + row scalars (wave 0) */
  if (tid < 64) {
    size_t rb = ((size_t)(rowb + tid)) * H_ + h;
    float la = log2f(f_al[rb]);
    #pragma unroll
    for (int m = 1; m < 64; m <<= 1) {
      float o = __shfl_up(la, m);
      if (tid >= m) la += o;
    }
    float L63 = __shfl(la, 63);
    float bt = f_be[rb];
    float g = exp2f(la);
    sL[tid] = la; sB[tid] = bt; sS2[tid] = bt * g;
    sDec[tid] = exp2f(L63 - la);
    if (tid == 63) sGC[0] = g;
    g_rs[(size_t)gid*256 + tid*4 + 0] = bt;
    g_rs[(size_t)gid*256 + tid*4 + 1] = bt * g;
    g_rs[(size_t)gid*256 + tid*4 + 2] = g;
  }
  __syncthreads();

  /* P2: packed-u32 staging of K^T and (beta*V)^T */
  {
    int tp = tid >> 3, q8 = tid & 7;
    int t0 = 2 * tp, t1 = 2 * tp + 1;
    const bf16x8 k0 = *(const bf16x8*)(b_k + (size_t)(rowb + t0) * D_ + hb + q8 * 8);
    const bf16x8 k1 = *(const bf16x8*)(b_k + (size_t)(rowb + t1) * D_ + hb + q8 * 8);
    const bf16x8 v0 = *(const bf16x8*)(b_v + (size_t)(rowb + t0) * D_ + hb + q8 * 8);
    const bf16x8 v1 = *(const bf16x8*)(b_v + (size_t)(rowb + t1) * D_ + hb + q8 * 8);
    float s0 = sB[t0], s1v = sB[t1];
    unsigned* KT32 = (unsigned*)sKT;
    unsigned* VT32 = (unsigned*)sVT;
    #pragma unroll
    for (int i = 0; i < 8; i++) {
      int k = q8 * 8 + i;
      KT32[k*40 + tp] = (unsigned)(unsigned short)k0[i] |
                        ((unsigned)(unsigned short)k1[i] << 16);
      unsigned lo = f2b(b2f((unsigned short)v0[i]) * s0);
      unsigned hi = f2b(b2f((unsigned short)v1[i]) * s1v);
      VT32[k*40 + tp] = lo | (hi << 16);
    }
  }
  /* P3: KK^T, QK^T -> sAb + g_Gqk */
  {
    bf16x8 bK[2], aK[4][2], aQ[4][2];
    #pragma unroll
    for (int k2 = 0; k2 < 2; k2++) {
      bK[k2] = *(const bf16x8*)&b_k[(size_t)(rowb + w*16 + l15)*D_ + hb + k2*32 + lg*8];
      #pragma unroll
      for (int ti = 0; ti < 4; ti++) {
        aK[ti][k2] = *(const bf16x8*)&b_k[(size_t)(rowb + ti*16 + l15)*D_ + hb + k2*32 + lg*8];
        aQ[ti][k2] = *(const bf16x8*)&b_q[(size_t)(rowb + ti*16 + l15)*D_ + hb + k2*32 + lg*8];
      }
    }
    f32x4 ck[4] = {}, cq[4] = {};
    #pragma unroll
    for (int k2 = 0; k2 < 2; k2++)
      #pragma unroll
      for (int ti = 0; ti < 4; ti++) {
        ck[ti] = MFMA_(aK[ti][k2], bK[k2], ck[ti]);
        cq[ti] = MFMA_(aQ[ti][k2], bK[k2], cq[ti]);
      }
    int j = w*16 + l15;
    float Lj = sL[j];
    #pragma unroll
    for (int ti = 0; ti < 4; ti++)
      #pragma unroll
      for (int r = 0; r < 4; r++) {
        int t = ti*16 + lg*4 + r;
        float ratio = exp2f(sL[t] - Lj);
        sAb[t*72 + j] = f2b((j < t) ? sB[t] * ratio * ck[ti][r] : 0.f);
        g_Gqk[g4 + t*64 + j] = f2b((j <= t) ? ratio * cq[ti][r] : 0.f);
      }
  }
  __syncthreads();
  /* P4: invert (I+Ab) -> sXb bf16; register-resident, quad-blocked */
  {
    int c = (w << 4) + (lane >> 2);
    int p = lane & 3;
    int rb16 = p << 4;
    float xr[16];
    #pragma unroll
    for (int j = 0; j < 16; j++) xr[j] = 0.f;
    #pragma unroll
    for (int q = 0; q < 16; q++) {
      int r0 = 4 * q;
      const unsigned short* abr = sAb + r0 * 72 + rb16;
      bf16x8 A0a = *(const bf16x8*)(abr);
      bf16x8 A0b = *(const bf16x8*)(abr + 8);
      bf16x8 A1a = *(const bf16x8*)(abr + 72);
      bf16x8 A1b = *(const bf16x8*)(abr + 80);
      bf16x8 A2a = *(const bf16x8*)(abr + 144);
      bf16x8 A2b = *(const bf16x8*)(abr + 152);
      bf16x8 A3a = *(const bf16x8*)(abr + 216);
      bf16x8 A3b = *(const bf16x8*)(abr + 224);
      float s0 = 0.f, s1 = 0.f, s2 = 0.f, s3 = 0.f;
      #pragma unroll
      for (int j = 0; j < 8; j++) {
        float xv = xr[j], xw = xr[8 + j];
        s0 = fmaf(b2f((unsigned short)A0a[j]), xv, s0);
        s1 = fmaf(b2f((unsigned short)A1a[j]), xv, s1);
        s2 = fmaf(b2f((unsigned short)A2a[j]), xv, s2);
        s3 = fmaf(b2f((unsigned short)A3a[j]), xv, s3);
        s0 = fmaf(b2f((unsigned short)A0b[j]), xw, s0);
        s1 = fmaf(b2f((unsigned short)A1b[j]), xw, s1);
        s2 = fmaf(b2f((unsigned short)A2b[j]), xw, s2);
        s3 = fmaf(b2f((unsigned short)A3b[j]), xw, s3);
      }
      s0 += __shfl_xor(s0, 1); s0 += __shfl_xor(s0, 2);
      s1 += __shfl_xor(s1, 1); s1 += __shfl_xor(s1, 2);
      s2 += __shfl_xor(s2, 1); s2 += __shfl_xor(s2, 2);
      s3 += __shfl_xor(s3, 1); s3 += __shfl_xor(s3, 2);
      float a10 = b2f(sAb[(r0+1)*72 + r0]);
      float a20 = b2f(sAb[(r0+2)*72 + r0]);
      float a21 = b2f(sAb[(r0+2)*72 + r0+1]);
      float a30 = b2f(sAb[(r0+3)*72 + r0]);
      float a31 = b2f(sAb[(r0+3)*72 + r0+1]);
      float a32 = b2f(sAb[(r0+3)*72 + r0+2]);
      float x0 = ((r0+0) == c ? 1.f : 0.f) - s0;
      float x1 = ((r0+1) == c ? 1.f : 0.f) - s1 - a10*x0;
      float x2 = ((r0+2) == c ? 1.f : 0.f) - s2 - a20*x0 - a21*x1;
      float x3 = ((r0+3) == c ? 1.f : 0.f) - s3 - a30*x0 - a31*x1 - a32*x2;
      if (p == (q >> 2)) {
        int ji = 4 * (q & 3);
        xr[ji+0] = x0; xr[ji+1] = x1; xr[ji+2] = x2; xr[ji+3] = x3;
      }
    }
    #pragma unroll
    for (int j = 0; j < 16; j++)
      sXb[(rb16 + j)*72 + c] = f2b(xr[j]);
  }
  __syncthreads();
  /* P5: Y^T (regs), Y -> g_Y, Z^T (regs + g_ZT) */
  int m0 = w * 16;
  f32x4 cyT[4], cz[4];
  {
    bf16x8 aKT[2];
    aKT[0] = *(const bf16x8*)&sKT[(m0 + l15)*80 + lg*8];
    aKT[1] = *(const bf16x8*)&sKT[(m0 + l15)*80 + 32 + lg*8];
    #pragma unroll
    for (int n = 0; n < 4; n++) {
      cyT[n] = f32x4{0.f, 0.f, 0.f, 0.f};
      #pragma unroll
      for (int k2 = 0; k2 < 2; k2++) {
        bf16x8 bb;
        #pragma unroll
        for (int i = 0; i < 8; i++) {
          int tp = k2*32 + lg*8 + i;
          bb[i] = (short)f2b(b2f(sXb[(n*16 + l15)*72 + tp]) * sS2[tp]);
        }
        cyT[n] = MFMA_(aKT[k2], bb, cyT[n]);
      }
    }
    bf16x8 aT2[2];
    #pragma unroll
    for (int k2 = 0; k2 < 2; k2++)
      #pragma unroll
      for (int i = 0; i < 8; i++) {
        int tp = k2*32 + lg*8 + i;
        aT2[k2][i] = (short)f2b(b2f(sXb[(m0 + l15)*72 + tp]) * sS2[tp]);
      }
    #pragma unroll
    for (int n = 0; n < 4; n++) {
      f32x4 c = {};
      #pragma unroll
      for (int k2 = 0; k2 < 2; k2++) {
        bf16x8 bKT = *(const bf16x8*)&sKT[(n*16 + l15)*80 + k2*32 + lg*8];
        c = MFMA_(aT2[k2], bKT, c);
      }
      #pragma unroll
      for (int r = 0; r < 4; r++)
        g_Y[g4 + (m0 + lg*4 + r)*64 + n*16 + l15] = f2b(c[r]);
    }
    bf16x8 aV[2];
    aV[0] = *(const bf16x8*)&sVT[(m0 + l15)*80 + lg*8];
    aV[1] = *(const bf16x8*)&sVT[(m0 + l15)*80 + 32 + lg*8];
    #pragma unroll
    for (int n = 0; n < 4; n++) {
      cz[n] = f32x4{0.f, 0.f, 0.f, 0.f};
      #pragma unroll
      for (int k2 = 0; k2 < 2; k2++) {
        bf16x8 bT = *(const bf16x8*)&sXb[(n*16 + l15)*72 + k2*32 + lg*8];
        cz[n] = MFMA_(aV[k2], bT, cz[n]);
      }
      #pragma unroll
      for (int r = 0; r < 4; r++)
        g_ZT[g4 + (m0 + lg*4 + r)*64 + n*16 + l15] = f2b(cz[n][r]);
    }
  }
  __syncthreads();
  /* P6: write Y^T (over sAb) + Z^T in place; P7: Kd = K^T*dec in place */
  #pragma unroll
  for (int n = 0; n < 4; n++)
    #pragma unroll
    for (int r = 0; r < 4; r++) {
      sYT[(m0 + lg*4 + r)*72 + n*16 + l15] = f2b(cyT[n][r]);
      sVT[(m0 + lg*4 + r)*80 + n*16 + l15] = f2b(cz[n][r]);
    }
  {
    int xx = tid >> 2, q = tid & 3;
    bf16x8 v0 = *(const bf16x8*)&sKT[xx*80 + q*16];
    bf16x8 v1 = *(const bf16x8*)&sKT[xx*80 + q*16 + 8];
    bf16x8 d0, d1;
    #pragma unroll
    for (int i = 0; i < 8; i++) {
      d0[i] = (short)f2b(b2f((unsigned short)v0[i]) * sDec[q*16 + i]);
      d1[i] = (short)f2b(b2f((unsigned short)v1[i]) * sDec[q*16 + 8 + i]);
    }
    *(bf16x8*)&sKT[xx*80 + q*16] = d0;
    *(bf16x8*)&sKT[xx*80 + q*16 + 8] = d1;
  }
  __syncthreads();
  /* P8: A = gC I - Kd*Y ; Bm^T = (Kd*Z)^T */
  {
    float gC = sGC[0];
    bf16x8 aKd[2];
    aKd[0] = *(const bf16x8*)&sKT[(m0 + l15)*80 + lg*8];
    aKd[1] = *(const bf16x8*)&sKT[(m0 + l15)*80 + 32 + lg*8];
    #pragma unroll
    for (int n = 0; n < 4; n++) {
      f32x4 c = {};
      #pragma unroll
      for (int k2 = 0; k2 < 2; k2++) {
        bf16x8 bY = *(const bf16x8*)&sYT[(n*16 + l15)*72 + k2*32 + lg*8];
        c = MFMA_(aKd[k2], bY, c);
      }
      #pragma unroll
      for (int r = 0; r < 4; r++) {
        int row = m0 + lg*4 + r, col = n*16 + l15;
        g_A[g4 + row*64 + col] = f2b(((row == col) ? gC : 0.f) - c[r]);
      }
    }
    #pragma unroll
    for (int n = 0; n < 4; n++) {
      f32x4 c = {};
      #pragma unroll
      for (int k2 = 0; k2 < 2; k2++) {
        bf16x8 bZ = *(const bf16x8*)&sVT[(n*16 + l15)*80 + k2*32 + lg*8];
        c = MFMA_(aKd[k2], bZ, c);
      }
      *(f32x4*)&g_BmT[g4 + (size_t)(n*16 + l15)*64 + m0 + lg*4] = c;
    }
  }
}

/* ---- seq: S' = A S + Bm per chunk; wave = v-strip, barrier-free ---- */
__global__ __launch_bounds__(256) void seq_k() {
  __shared__ __align__(16) unsigned short sST[4][16*80];
  int bh = blockIdx.x;
  int tid = threadIdx.x, w = tid >> 6, lane = tid & 63;
  int l15 = lane & 15, lg = lane >> 4;
  unsigned short* st = sST[w];
  for (int i = lane; i < 16*80; i += 64) st[i] = 0;
  f32x4 cerr[4] = {};
  bf16x8 aA[4][2];
  f32x4 cini[4];
  size_t g40 = (size_t)(bh * 32) * 4096;
  #pragma unroll
  for (int m = 0; m < 4; m++) {
    aA[m][0] = *(const bf16x8*)&g_A[g40 + (m*16 + l15)*64 + lg*8];
    aA[m][1] = *(const bf16x8*)&g_A[g40 + (m*16 + l15)*64 + 32 + lg*8];
    cini[m] = *(const f32x4*)&g_BmT[g40 + (w*16 + l15)*64 + m*16 + lg*4];
  }
  for (int ch = 0; ch < NCH_; ch++) {
    size_t gid = (size_t)bh * 32 + ch;
    float gC = g_rs[gid*256 + 254];
    bf16x8 bS0 = *(const bf16x8*)&st[l15*80 + lg*8];
    bf16x8 bS1 = *(const bf16x8*)&st[l15*80 + 32 + lg*8];
    *(bf16x8*)&g_S[gid*4096 + (w*16 + l15)*64 + lg*8] = bS0;
    *(bf16x8*)&g_S[gid*4096 + (w*16 + l15)*64 + 32 + lg*8] = bS1;
    bf16x8 aAn[4][2];
    f32x4 cin2[4];
    if (ch + 1 < NCH_) {
      size_t g4n = (gid + 1) * 4096;
      #pragma unroll
      for (int m = 0; m < 4; m++) {
        aAn[m][0] = *(const bf16x8*)&g_A[g4n + (m*16 + l15)*64 + lg*8];
        aAn[m][1] = *(const bf16x8*)&g_A[g4n + (m*16 + l15)*64 + 32 + lg*8];
        cin2[m] = *(const f32x4*)&g_BmT[g4n + (w*16 + l15)*64 + m*16 + lg*4];
      }
    }
    f32x4 c[4];
    #pragma unroll
    for (int m = 0; m < 4; m++) {
      #pragma unroll
      for (int r = 0; r < 4; r++)
        c[m][r] = cini[m][r] + gC * cerr[m][r];
      c[m] = MFMA_(aA[m][0], bS0, c[m]);
      c[m] = MFMA_(aA[m][1], bS1, c[m]);
    }
    #pragma unroll
    for (int m = 0; m < 4; m++)
      #pragma unroll
      for (int r = 0; r < 4; r++) {
        float x = c[m][r];
        unsigned short q = f2b(x);
        cerr[m][r] = x - b2f(q);
        st[l15*80 + m*16 + lg*4 + r] = q;
      }
    if (ch + 1 < NCH_) {
      #pragma unroll
      for (int m = 0; m < 4; m++) {
        aA[m][0] = aAn[m][0]; aA[m][1] = aAn[m][1];
        cini[m] = cin2[m];
      }
    }
  }
}

/* ---- apply: U^T = Z^T - S^T Y^T ; O^T = gam (QS)^T + (Gqk U)^T ---- */
__global__ __launch_bounds__(256) void apply_k() {
  __shared__ __align__(16) unsigned short sUT[4][16*80];
  int gid = blockIdx.x;
  int ch = gid & 31, bh = gid >> 5;
  int b = bh >> 4, h = bh & 15;
  int c0 = ch * 64, hb = h * HD_;
  int rowb = b * T_ + c0;
  int tid = threadIdx.x, w = tid >> 6, lane = tid & 63;
  int l15 = lane & 15, lg = lane >> 4;
  unsigned short* ut = sUT[w];
  size_t g4 = (size_t)gid * 4096;
  bf16x8 aS[2];
  aS[0] = *(const bf16x8*)&g_S[g4 + (w*16 + l15)*64 + lg*8];
  aS[1] = *(const bf16x8*)&g_S[g4 + (w*16 + l15)*64 + 32 + lg*8];
  f32x4 cu[4];
  #pragma unroll
  for (int n = 0; n < 4; n++) {
    cu[n] = f32x4{0.f, 0.f, 0.f, 0.f};
    #pragma unroll
    for (int k2 = 0; k2 < 2; k2++) {
      bf16x8 bY = *(const bf16x8*)&g_Y[g4 + (n*16 + l15)*64 + k2*32 + lg*8];
      cu[n] = MFMA_(aS[k2], bY, cu[n]);
    }
  }
  #pragma unroll
  for (int n = 0; n < 4; n++)
    #pragma unroll
    for (int r = 0; r < 4; r++) {
      float zt = b2f(g_ZT[g4 + (w*16 + lg*4 + r)*64 + n*16 + l15]);
      ut[(lg*4 + r)*80 + n*16 + l15] = f2b(zt - cu[n][r]);
    }
  bf16x8 aU[2];
  aU[0] = *(const bf16x8*)&ut[l15*80 + lg*8];
  aU[1] = *(const bf16x8*)&ut[l15*80 + 32 + lg*8];
  f32x4 co[4];
  #pragma unroll
  for (int n = 0; n < 4; n++) {
    co[n] = f32x4{0.f, 0.f, 0.f, 0.f};
    #pragma unroll
    for (int k2 = 0; k2 < 2; k2++) {
      bf16x8 bQ = *(const bf16x8*)&b_q[(size_t)(rowb + n*16 + l15)*D_ + hb + k2*32 + lg*8];
      co[n] = MFMA_(aS[k2], bQ, co[n]);
    }
    float gm = g_rs[(size_t)gid*256 + (n*16 + l15)*4 + 2];
    #pragma unroll
    for (int r = 0; r < 4; r++) co[n][r] *= gm;
    #pragma unroll
    for (int k2 = 0; k2 < 2; k2++) {
      bf16x8 bG = *(const bf16x8*)&g_Gqk[g4 + (n*16 + l15)*64 + k2*32 + lg*8];
      co[n] = MFMA_(aU[k2], bG, co[n]);
    }
    ushort4 pk;
    pk.x = f2b(co[n][0]); pk.y = f2b(co[n][1]);
    pk.z = f2b(co[n][2]); pk.w = f2b(co[n][3]);
    *(ushort4*)&b_o[(size_t)(rowb + n*16 + l15)*D_ + hb + w*16 + lg*4] = pk;
  }
}

extern "C" void kernel_launch(void* const* d_in, const int* in_sizes, int n_in,
                              void* d_out, int out_size, void* d_ws, size_t ws_size,
                              hipStream_t stream) {
  const float* x   = (const float*)d_in[0];
  const float* n1w = (const float*)d_in[1];
  const float* n2w = (const float*)d_in[2];
  const float* cw  = (const float*)d_in[3];
  const float* cb  = (const float*)d_in[4];
  const float* wq  = (const float*)d_in[5];
  const float* wk  = (const float*)d_in[6];
  const float* wv  = (const float*)d_in[7];
  const float* wb  = (const float*)d_in[8];
  const float* wa  = (const float*)d_in[9];
  const float* wo  = (const float*)d_in[10];
  const float* wg  = (const float*)d_in[11];
  const float* wu  = (const float*)d_in[12];
  const float* wd  = (const float*)d_in[13];
  float* out = (float*)d_out;

  /* weight preprocessing */
  castTqkv_k<<<dim3(52, 16), 256, 0, stream>>>(wq, wk, wv, wb, wa);
  castT_k<<<dim3(16, 16), 256, 0, stream>>>(wo, D_, D_, 5, D_);
  castTgu_k<<<dim3(88, 16), 256, 0, stream>>>(wg, wu);
  castT_k<<<dim3(16, 44), 256, 0, stream>>>(wd, I_, D_, 7, IP_);

  /* norm1 scale + fused norm/conv/silu */
  rmssc_k<<<BT_, 256, 0, stream>>>(x);
  conv2_k<<<ND_ / 256, 256, 0, stream>>>(x, cw, cb, n1w);

  /* fused QKV+gates GEMM, 256x256 8-wave BK=64 4-phase v2 (early staging) */
  gemm256<<<dim3(13, 16), 512, 0, stream>>>(0, 4, D_, 0);

  /* chunked WY delta rule: parallel prep, tiny serial scan, parallel apply */
  prep_k<<<NG_, 256, 0, stream>>>();
  seq_k<<<32, 256, 0, stream>>>();
  apply_k<<<NG_, 256, 0, stream>>>();

  /* mix = o@wo + x -> f_h (128^2 kernel) */
  gemm_bf16<<<dim3(8, 32), 256, 0, stream>>>(1, 5, D_, 2, x, nullptr);
  /* hn = rmsnorm(h) -> b_hn */
  rms2_k<<<BT_, 256, 0, stream>>>(n2w);
  /* g,u fused GEMM + swiglu, 256x256 8-wave BK=64 4-phase v2 -> b_f */
  gemm256<<<dim3(22, 16), 512, 0, stream>>>(2, 6, D_, 1);
  /* ffn = f@wd + h -> out (128^2 kernel) */
  gemm_bf16<<<dim3(8, 32), 256, 0, stream>>>(3, 7, IP_, 3, nullptr, out);
}